// Round 1
// baseline (952.775 us; speedup 1.0000x reference)
//
#include <hip/hip_runtime.h>
#include <hip/hip_bf16.h>
#include <math.h>

#define LRELU(a) ((a) > 0.f ? (a) : 0.2f * (a))

// ---------------- CSR build ----------------

__global__ void hist_kernel(const int* __restrict__ dst, const float* __restrict__ eattr,
                            int* __restrict__ cnt_i, float* __restrict__ attr_sum, int E) {
    int e = blockIdx.x * blockDim.x + threadIdx.x;
    if (e < E) {
        int d = dst[e];
        atomicAdd(&cnt_i[d], 1);
        atomicAdd(&attr_sum[d], eattr[e]);
    }
}

__global__ __launch_bounds__(1024) void scan_build_kernel(
        const int* __restrict__ cnt_i, const float* __restrict__ attr_sum,
        int* __restrict__ row_ptr, int* __restrict__ cursor,
        int* __restrict__ col_src, float* __restrict__ col_attr, int N) {
    __shared__ int partial[1024];
    int t = threadIdx.x;
    int chunk = (N + 1023) >> 10;
    int lo = t * chunk, hi = min(lo + chunk, N);
    int s = 0;
    for (int n = lo; n < hi; n++) s += cnt_i[n] + 1;  // +1 self loop
    partial[t] = s;
    __syncthreads();
    // Hillis-Steele inclusive scan over 1024 partials
    for (int off = 1; off < 1024; off <<= 1) {
        int v = partial[t];
        int u = (t >= off) ? partial[t - off] : 0;
        __syncthreads();
        partial[t] = v + u;
        __syncthreads();
    }
    if (t == 1023) row_ptr[N] = partial[1023];
    int run = (t == 0) ? 0 : partial[t - 1];
    for (int n = lo; n < hi; n++) {
        row_ptr[n] = run;
        int c = cnt_i[n];
        float la = attr_sum[n] / fmaxf((float)c, 1.f);  // fill_value='mean' self-loop attr
        col_src[run] = n;                                // self loop first in row
        col_attr[run] = la;
        cursor[n] = run + 1;
        run += c + 1;
    }
}

__global__ void scatter_kernel(const int* __restrict__ src, const int* __restrict__ dst,
                               const float* __restrict__ eattr, int* __restrict__ cursor,
                               int* __restrict__ col_src, float* __restrict__ col_attr, int E) {
    int e = blockIdx.x * blockDim.x + threadIdx.x;
    if (e < E) {
        int d = dst[e];
        int pos = atomicAdd(&cursor[d], 1);
        col_src[pos] = src[e];
        col_attr[pos] = eattr[e];
    }
}

// ---------------- per-layer node projection: xh = feat @ W, al_s/al_d dots ----------------

template<int FIN>
__global__ __launch_bounds__(128) void node_proj_kernel(
        const float* __restrict__ feat, const float* __restrict__ W,
        const float* __restrict__ as_, const float* __restrict__ ad_,
        float* __restrict__ xh, float* __restrict__ al_s, float* __restrict__ al_d, int N) {
    __shared__ float sf[FIN];
    int n = blockIdx.x;
    if (n >= N) return;
    int j = threadIdx.x;  // 0..127  (h = j>>6, c = j&63)
    if (j < FIN) sf[j] = feat[(size_t)n * FIN + j];
    __syncthreads();
    float acc = 0.f;
#pragma unroll
    for (int k = 0; k < FIN; k++) acc += sf[k] * W[k * 128 + j];
    xh[(size_t)n * 128 + j] = acc;
    float vs = acc * as_[j];
    float vd = acc * ad_[j];
#pragma unroll
    for (int m = 32; m >= 1; m >>= 1) {
        vs += __shfl_xor(vs, m);
        vd += __shfl_xor(vd, m);
    }
    if ((j & 63) == 0) {
        int h = j >> 6;
        al_s[n * 2 + h] = vs;
        al_d[n * 2 + h] = vd;
    }
}

// al_e[e,h] = eattr[e] * dot(We[h,:], ae[h,:])  -> precompute the 4 scalars (2 layers x 2 heads)
__global__ __launch_bounds__(256) void wedot_kernel(const float* __restrict__ We1, const float* __restrict__ ae1,
                                                    const float* __restrict__ We2, const float* __restrict__ ae2,
                                                    float* __restrict__ we_dot) {
    int t = threadIdx.x;
    int g = t >> 6, lane = t & 63;          // g = layer*2 + h
    const float* We = (g & 2) ? We2 : We1;
    const float* ae = (g & 2) ? ae2 : ae1;
    int h = g & 1;
    float v = We[h * 64 + lane] * ae[h * 64 + lane];
#pragma unroll
    for (int m = 32; m >= 1; m >>= 1) v += __shfl_xor(v, m);
    if (lane == 0) we_dot[g] = v;
}

// ---------------- edge aggregation: segment softmax + weighted sum, one wave per dst ----------------

__global__ __launch_bounds__(64) void edge_aggr_kernel(
        const int* __restrict__ row_ptr, const int* __restrict__ col_src, const float* __restrict__ col_attr,
        const float* __restrict__ al_s, const float* __restrict__ al_d, const float* __restrict__ xh,
        const float* __restrict__ bias, const float* __restrict__ we_dot, int layer,
        float* __restrict__ out, int N) {
    __shared__ float s_ex0[64], s_ex1[64];
    __shared__ int s_src[64];
    int n = blockIdx.x;
    if (n >= N) return;
    int lane = threadIdx.x;
    int start = row_ptr[n], end = row_ptr[n + 1];
    float we0 = we_dot[layer * 2], we1 = we_dot[layer * 2 + 1];
    float ald0 = al_d[2 * n], ald1 = al_d[2 * n + 1];

    // pass 1: per-head max over incoming edges (segment_max)
    float m0 = -INFINITY, m1 = -INFINITY;
    for (int i = start + lane; i < end; i += 64) {
        int sc = col_src[i];
        float at = col_attr[i];
        float a0 = al_s[2 * sc] + ald0 + we0 * at;
        float a1 = al_s[2 * sc + 1] + ald1 + we1 * at;
        a0 = LRELU(a0); a1 = LRELU(a1);
        m0 = fmaxf(m0, a0); m1 = fmaxf(m1, a1);
    }
#pragma unroll
    for (int m = 32; m >= 1; m >>= 1) {
        m0 = fmaxf(m0, __shfl_xor(m0, m));
        m1 = fmaxf(m1, __shfl_xor(m1, m));
    }

    // pass 2: unnormalized accumulation (att = ex/den is linear -> normalize at the end)
    float den0 = 0.f, den1 = 0.f, acc0 = 0.f, acc1 = 0.f;
    for (int cs = start; cs < end; cs += 64) {
        int i = cs + lane;
        float e0 = 0.f, e1 = 0.f;
        int sc = 0;
        if (i < end) {
            sc = col_src[i];
            float at = col_attr[i];
            float a0 = al_s[2 * sc] + ald0 + we0 * at;
            float a1 = al_s[2 * sc + 1] + ald1 + we1 * at;
            a0 = LRELU(a0); a1 = LRELU(a1);
            e0 = expf(a0 - m0);
            e1 = expf(a1 - m1);
        }
        den0 += e0; den1 += e1;
        s_ex0[lane] = e0; s_ex1[lane] = e1; s_src[lane] = sc;
        __syncthreads();
        int cnt = min(64, end - cs);
        for (int j = 0; j < cnt; j++) {
            float w0 = s_ex0[j], w1 = s_ex1[j];
            size_t sj = (size_t)s_src[j] * 128;
            acc0 += w0 * xh[sj + lane];        // head 0 channels
            acc1 += w1 * xh[sj + 64 + lane];   // head 1 channels
        }
        __syncthreads();
    }
#pragma unroll
    for (int m = 32; m >= 1; m >>= 1) {
        den0 += __shfl_xor(den0, m);
        den1 += __shfl_xor(den1, m);
    }
    float o = 0.5f * (acc0 / (den0 + 1e-16f) + acc1 / (den1 + 1e-16f)) + bias[lane];
    out[(size_t)n * 64 + lane] = fmaxf(o, 0.f);  // relu fused
}

// ---------------- pooling: out[g] = (sum_n dot(h[n], Wlin)) / cnt_g + blin ----------------

__global__ __launch_bounds__(256) void pool_kernel(const float* __restrict__ feat,
                                                   const float* __restrict__ Wlin, const int* __restrict__ batch,
                                                   float* __restrict__ pool_sum, float* __restrict__ pool_cnt, int N) {
    int node = blockIdx.x * 4 + (threadIdx.x >> 6);
    int lane = threadIdx.x & 63;
    if (node >= N) return;
    float v = feat[(size_t)node * 64 + lane] * Wlin[lane];
#pragma unroll
    for (int m = 32; m >= 1; m >>= 1) v += __shfl_xor(v, m);
    if (lane == 0) {
        int g = batch[node];
        atomicAdd(&pool_sum[g], v);
        atomicAdd(&pool_cnt[g], 1.f);
    }
}

__global__ void final_kernel(const float* __restrict__ pool_sum, const float* __restrict__ pool_cnt,
                             const float* __restrict__ blin, float* __restrict__ out) {
    int g = threadIdx.x;
    if (g < 64) out[g] = pool_sum[g] / fmaxf(pool_cnt[g], 1.f) + blin[0];
}

// ---------------- launch ----------------

extern "C" void kernel_launch(void* const* d_in, const int* in_sizes, int n_in,
                              void* d_out, int out_size, void* d_ws, size_t ws_size,
                              hipStream_t stream) {
    const float* x     = (const float*)d_in[0];
    const int*   ei    = (const int*)d_in[1];
    const float* eattr = (const float*)d_in[2];
    const int*   batch = (const int*)d_in[3];
    const float* W1  = (const float*)d_in[4];
    const float* as1 = (const float*)d_in[5];
    const float* ad1 = (const float*)d_in[6];
    const float* We1 = (const float*)d_in[7];
    const float* ae1 = (const float*)d_in[8];
    const float* b1  = (const float*)d_in[9];
    const float* W2  = (const float*)d_in[10];
    const float* as2 = (const float*)d_in[11];
    const float* ad2 = (const float*)d_in[12];
    const float* We2 = (const float*)d_in[13];
    const float* ae2 = (const float*)d_in[14];
    const float* b2  = (const float*)d_in[15];
    const float* Wlin = (const float*)d_in[16];
    const float* blin = (const float*)d_in[17];
    float* out = (float*)d_out;

    int N = in_sizes[0] / 5;
    int E = in_sizes[1] / 2;
    size_t EP = (size_t)E + N;
    const int* src0 = ei;
    const int* dst0 = ei + E;

    char* ws = (char*)d_ws;
    size_t off = 0;
    auto alloc = [&](size_t bytes) {
        void* p = ws + off;
        off = (off + bytes + 255) & ~(size_t)255;
        return p;
    };
    int*   cnt_i    = (int*)  alloc((size_t)N * 4);
    float* attr_sum = (float*)alloc((size_t)N * 4);
    int*   row_ptr  = (int*)  alloc((size_t)(N + 1) * 4);
    int*   cursor   = (int*)  alloc((size_t)N * 4);
    int*   col_src  = (int*)  alloc(EP * 4);
    float* col_attr = (float*)alloc(EP * 4);
    float* al_s     = (float*)alloc((size_t)N * 2 * 4);
    float* al_d     = (float*)alloc((size_t)N * 2 * 4);
    float* xh       = (float*)alloc((size_t)N * 128 * 4);
    float* feat1    = (float*)alloc((size_t)N * 64 * 4);
    float* feat2    = (float*)alloc((size_t)N * 64 * 4);
    float* we_dot   = (float*)alloc(4 * 4);
    float* pool_sum = (float*)alloc(64 * 4);
    float* pool_cnt = (float*)alloc(64 * 4);

    hipMemsetAsync(cnt_i, 0, (size_t)N * 4, stream);
    hipMemsetAsync(attr_sum, 0, (size_t)N * 4, stream);
    hipMemsetAsync(pool_sum, 0, 64 * 4, stream);
    hipMemsetAsync(pool_cnt, 0, 64 * 4, stream);

    hist_kernel<<<(E + 255) / 256, 256, 0, stream>>>(dst0, eattr, cnt_i, attr_sum, E);
    scan_build_kernel<<<1, 1024, 0, stream>>>(cnt_i, attr_sum, row_ptr, cursor, col_src, col_attr, N);
    scatter_kernel<<<(E + 255) / 256, 256, 0, stream>>>(src0, dst0, eattr, cursor, col_src, col_attr, E);
    wedot_kernel<<<1, 256, 0, stream>>>(We1, ae1, We2, ae2, we_dot);

    // layer 1
    node_proj_kernel<5><<<N, 128, 0, stream>>>(x, W1, as1, ad1, xh, al_s, al_d, N);
    edge_aggr_kernel<<<N, 64, 0, stream>>>(row_ptr, col_src, col_attr, al_s, al_d, xh, b1, we_dot, 0, feat1, N);
    // layer 2
    node_proj_kernel<64><<<N, 128, 0, stream>>>(feat1, W2, as2, ad2, xh, al_s, al_d, N);
    edge_aggr_kernel<<<N, 64, 0, stream>>>(row_ptr, col_src, col_attr, al_s, al_d, xh, b2, we_dot, 1, feat2, N);
    // pool + linear
    pool_kernel<<<(N + 3) / 4, 256, 0, stream>>>(feat2, Wlin, batch, pool_sum, pool_cnt, N);
    final_kernel<<<1, 64, 0, stream>>>(pool_sum, pool_cnt, blin, out);
}

// Round 2
// 584.440 us; speedup vs baseline: 1.6302x; 1.6302x over previous
//
#include <hip/hip_runtime.h>
#include <hip/hip_bf16.h>
#include <math.h>

#define LRELU(a) ((a) > 0.f ? (a) : 0.2f * (a))

// ---------------- CSR build ----------------

__global__ void hist_kernel(const int* __restrict__ dst, const float* __restrict__ eattr,
                            int* __restrict__ cnt_i, float* __restrict__ attr_sum, int E) {
    int e = blockIdx.x * blockDim.x + threadIdx.x;
    if (e < E) {
        int d = dst[e];
        atomicAdd(&cnt_i[d], 1);
        atomicAdd(&attr_sum[d], eattr[e]);
    }
}

__global__ __launch_bounds__(1024) void scan_build_kernel(
        const int* __restrict__ cnt_i, const float* __restrict__ attr_sum,
        int* __restrict__ row_ptr, int* __restrict__ cursor,
        int* __restrict__ col_src, float* __restrict__ col_attr, int N) {
    __shared__ int partial[1024];
    int t = threadIdx.x;
    int chunk = (N + 1023) >> 10;
    int lo = t * chunk, hi = min(lo + chunk, N);
    int s = 0;
    for (int n = lo; n < hi; n++) s += cnt_i[n] + 1;  // +1 self loop
    partial[t] = s;
    __syncthreads();
    // Hillis-Steele inclusive scan over 1024 partials
    for (int off = 1; off < 1024; off <<= 1) {
        int v = partial[t];
        int u = (t >= off) ? partial[t - off] : 0;
        __syncthreads();
        partial[t] = v + u;
        __syncthreads();
    }
    if (t == 1023) row_ptr[N] = partial[1023];
    int run = (t == 0) ? 0 : partial[t - 1];
    for (int n = lo; n < hi; n++) {
        row_ptr[n] = run;
        int c = cnt_i[n];
        float la = attr_sum[n] / fmaxf((float)c, 1.f);  // fill_value='mean' self-loop attr
        col_src[run] = n;                                // self loop first in row
        col_attr[run] = la;
        cursor[n] = run + 1;
        run += c + 1;
    }
}

__global__ void scatter_kernel(const int* __restrict__ src, const int* __restrict__ dst,
                               const float* __restrict__ eattr, int* __restrict__ cursor,
                               int* __restrict__ col_src, float* __restrict__ col_attr, int E) {
    int e = blockIdx.x * blockDim.x + threadIdx.x;
    if (e < E) {
        int d = dst[e];
        int pos = atomicAdd(&cursor[d], 1);
        col_src[pos] = src[e];
        col_attr[pos] = eattr[e];
    }
}

// ---------------- per-layer node projection: xh = feat @ W, al_s/al_d dots ----------------

template<int FIN>
__global__ __launch_bounds__(128) void node_proj_kernel(
        const float* __restrict__ feat, const float* __restrict__ W,
        const float* __restrict__ as_, const float* __restrict__ ad_,
        float* __restrict__ xh, float* __restrict__ al_s, float* __restrict__ al_d, int N) {
    __shared__ float sf[FIN];
    int n = blockIdx.x;
    if (n >= N) return;
    int j = threadIdx.x;  // 0..127  (h = j>>6, c = j&63)
    if (j < FIN) sf[j] = feat[(size_t)n * FIN + j];
    __syncthreads();
    float acc = 0.f;
#pragma unroll
    for (int k = 0; k < FIN; k++) acc += sf[k] * W[k * 128 + j];
    xh[(size_t)n * 128 + j] = acc;
    float vs = acc * as_[j];
    float vd = acc * ad_[j];
#pragma unroll
    for (int m = 32; m >= 1; m >>= 1) {
        vs += __shfl_xor(vs, m);
        vd += __shfl_xor(vd, m);
    }
    if ((j & 63) == 0) {
        int h = j >> 6;
        al_s[n * 2 + h] = vs;
        al_d[n * 2 + h] = vd;
    }
}

// al_e[e,h] = eattr[e] * dot(We[h,:], ae[h,:])  -> precompute the 4 scalars (2 layers x 2 heads)
__global__ __launch_bounds__(256) void wedot_kernel(const float* __restrict__ We1, const float* __restrict__ ae1,
                                                    const float* __restrict__ We2, const float* __restrict__ ae2,
                                                    float* __restrict__ we_dot) {
    int t = threadIdx.x;
    int g = t >> 6, lane = t & 63;          // g = layer*2 + h
    const float* We = (g & 2) ? We2 : We1;
    const float* ae = (g & 2) ? ae2 : ae1;
    int h = g & 1;
    float v = We[h * 64 + lane] * ae[h * 64 + lane];
#pragma unroll
    for (int m = 32; m >= 1; m >>= 1) v += __shfl_xor(v, m);
    if (lane == 0) we_dot[g] = v;
}

// ---------------- edge aggregation: segment softmax + weighted sum, one wave per dst ----------------

__global__ __launch_bounds__(64) void edge_aggr_kernel(
        const int* __restrict__ row_ptr, const int* __restrict__ col_src, const float* __restrict__ col_attr,
        const float* __restrict__ al_s, const float* __restrict__ al_d, const float* __restrict__ xh,
        const float* __restrict__ bias, const float* __restrict__ we_dot, int layer,
        float* __restrict__ out, int N) {
    __shared__ float s_ex0[64], s_ex1[64];
    __shared__ int s_src[64];
    int n = blockIdx.x;
    if (n >= N) return;
    int lane = threadIdx.x;
    int start = row_ptr[n], end = row_ptr[n + 1];
    float we0 = we_dot[layer * 2], we1 = we_dot[layer * 2 + 1];
    float ald0 = al_d[2 * n], ald1 = al_d[2 * n + 1];

    // pass 1: per-head max over incoming edges (segment_max)
    float m0 = -INFINITY, m1 = -INFINITY;
    for (int i = start + lane; i < end; i += 64) {
        int sc = col_src[i];
        float at = col_attr[i];
        float a0 = al_s[2 * sc] + ald0 + we0 * at;
        float a1 = al_s[2 * sc + 1] + ald1 + we1 * at;
        a0 = LRELU(a0); a1 = LRELU(a1);
        m0 = fmaxf(m0, a0); m1 = fmaxf(m1, a1);
    }
#pragma unroll
    for (int m = 32; m >= 1; m >>= 1) {
        m0 = fmaxf(m0, __shfl_xor(m0, m));
        m1 = fmaxf(m1, __shfl_xor(m1, m));
    }

    // pass 2: unnormalized accumulation (att = ex/den is linear -> normalize at the end)
    float den0 = 0.f, den1 = 0.f, acc0 = 0.f, acc1 = 0.f;
    for (int cs = start; cs < end; cs += 64) {
        int i = cs + lane;
        float e0 = 0.f, e1 = 0.f;
        int sc = 0;
        if (i < end) {
            sc = col_src[i];
            float at = col_attr[i];
            float a0 = al_s[2 * sc] + ald0 + we0 * at;
            float a1 = al_s[2 * sc + 1] + ald1 + we1 * at;
            a0 = LRELU(a0); a1 = LRELU(a1);
            e0 = expf(a0 - m0);
            e1 = expf(a1 - m1);
        }
        den0 += e0; den1 += e1;
        s_ex0[lane] = e0; s_ex1[lane] = e1; s_src[lane] = sc;
        __syncthreads();
        int cnt = min(64, end - cs);
        for (int j = 0; j < cnt; j++) {
            float w0 = s_ex0[j], w1 = s_ex1[j];
            size_t sj = (size_t)s_src[j] * 128;
            acc0 += w0 * xh[sj + lane];        // head 0 channels
            acc1 += w1 * xh[sj + 64 + lane];   // head 1 channels
        }
        __syncthreads();
    }
#pragma unroll
    for (int m = 32; m >= 1; m >>= 1) {
        den0 += __shfl_xor(den0, m);
        den1 += __shfl_xor(den1, m);
    }
    float o = 0.5f * (acc0 / (den0 + 1e-16f) + acc1 / (den1 + 1e-16f)) + bias[lane];
    out[(size_t)n * 64 + lane] = fmaxf(o, 0.f);  // relu fused
}

// ---------------- pooling: hierarchical (LDS bins -> few global atomics) ----------------
// out[g] = (sum_{n in g} dot(h[n], Wlin)) / cnt_g + blin
// batch is sorted, so a contiguous node chunk touches ~1-2 graphs -> flush only touched bins.

__global__ __launch_bounds__(256) void pool_kernel(const float* __restrict__ feat,
                                                   const float* __restrict__ Wlin, const int* __restrict__ batch,
                                                   float* __restrict__ pool_sum, int* __restrict__ pool_cnt, int N) {
    __shared__ float s_sum[64];
    __shared__ int s_cnt[64];
    int t = threadIdx.x;
    if (t < 64) { s_sum[t] = 0.f; s_cnt[t] = 0; }
    __syncthreads();

    int nblk = gridDim.x;
    int chunk = (N + nblk - 1) / nblk;
    int lo = blockIdx.x * chunk;
    int hi = min(lo + chunk, N);
    int lane = t & 63;
    float wl = Wlin[lane];

    for (int node = lo + (t >> 6); node < hi; node += 4) {
        float v = feat[(size_t)node * 64 + lane] * wl;
#pragma unroll
        for (int m = 32; m >= 1; m >>= 1) v += __shfl_xor(v, m);
        if (lane == 0) {
            int g = batch[node];
            atomicAdd(&s_sum[g], v);
            atomicAdd(&s_cnt[g], 1);
        }
    }
    __syncthreads();
    if (t < 64 && s_cnt[t] > 0) {
        atomicAdd(&pool_sum[t], s_sum[t]);
        atomicAdd(&pool_cnt[t], s_cnt[t]);
    }
}

__global__ void final_kernel(const float* __restrict__ pool_sum, const int* __restrict__ pool_cnt,
                             const float* __restrict__ blin, float* __restrict__ out) {
    int g = threadIdx.x;
    if (g < 64) out[g] = pool_sum[g] / fmaxf((float)pool_cnt[g], 1.f) + blin[0];
}

// ---------------- launch ----------------

extern "C" void kernel_launch(void* const* d_in, const int* in_sizes, int n_in,
                              void* d_out, int out_size, void* d_ws, size_t ws_size,
                              hipStream_t stream) {
    const float* x     = (const float*)d_in[0];
    const int*   ei    = (const int*)d_in[1];
    const float* eattr = (const float*)d_in[2];
    const int*   batch = (const int*)d_in[3];
    const float* W1  = (const float*)d_in[4];
    const float* as1 = (const float*)d_in[5];
    const float* ad1 = (const float*)d_in[6];
    const float* We1 = (const float*)d_in[7];
    const float* ae1 = (const float*)d_in[8];
    const float* b1  = (const float*)d_in[9];
    const float* W2  = (const float*)d_in[10];
    const float* as2 = (const float*)d_in[11];
    const float* ad2 = (const float*)d_in[12];
    const float* We2 = (const float*)d_in[13];
    const float* ae2 = (const float*)d_in[14];
    const float* b2  = (const float*)d_in[15];
    const float* Wlin = (const float*)d_in[16];
    const float* blin = (const float*)d_in[17];
    float* out = (float*)d_out;

    int N = in_sizes[0] / 5;
    int E = in_sizes[1] / 2;
    size_t EP = (size_t)E + N;
    const int* src0 = ei;
    const int* dst0 = ei + E;

    char* ws = (char*)d_ws;
    size_t off = 0;
    auto alloc = [&](size_t bytes) {
        void* p = ws + off;
        off = (off + bytes + 255) & ~(size_t)255;
        return p;
    };
    int*   cnt_i    = (int*)  alloc((size_t)N * 4);
    float* attr_sum = (float*)alloc((size_t)N * 4);
    int*   row_ptr  = (int*)  alloc((size_t)(N + 1) * 4);
    int*   cursor   = (int*)  alloc((size_t)N * 4);
    int*   col_src  = (int*)  alloc(EP * 4);
    float* col_attr = (float*)alloc(EP * 4);
    float* al_s     = (float*)alloc((size_t)N * 2 * 4);
    float* al_d     = (float*)alloc((size_t)N * 2 * 4);
    float* xh       = (float*)alloc((size_t)N * 128 * 4);
    float* feat1    = (float*)alloc((size_t)N * 64 * 4);
    float* feat2    = (float*)alloc((size_t)N * 64 * 4);
    float* we_dot   = (float*)alloc(4 * 4);
    float* pool_sum = (float*)alloc(64 * 4);
    int*   pool_cnt = (int*)  alloc(64 * 4);

    hipMemsetAsync(cnt_i, 0, (size_t)N * 4, stream);
    hipMemsetAsync(attr_sum, 0, (size_t)N * 4, stream);
    hipMemsetAsync(pool_sum, 0, 64 * 4, stream);
    hipMemsetAsync(pool_cnt, 0, 64 * 4, stream);

    hist_kernel<<<(E + 255) / 256, 256, 0, stream>>>(dst0, eattr, cnt_i, attr_sum, E);
    scan_build_kernel<<<1, 1024, 0, stream>>>(cnt_i, attr_sum, row_ptr, cursor, col_src, col_attr, N);
    scatter_kernel<<<(E + 255) / 256, 256, 0, stream>>>(src0, dst0, eattr, cursor, col_src, col_attr, E);
    wedot_kernel<<<1, 256, 0, stream>>>(We1, ae1, We2, ae2, we_dot);

    // layer 1
    node_proj_kernel<5><<<N, 128, 0, stream>>>(x, W1, as1, ad1, xh, al_s, al_d, N);
    edge_aggr_kernel<<<N, 64, 0, stream>>>(row_ptr, col_src, col_attr, al_s, al_d, xh, b1, we_dot, 0, feat1, N);
    // layer 2
    node_proj_kernel<64><<<N, 128, 0, stream>>>(feat1, W2, as2, ad2, xh, al_s, al_d, N);
    edge_aggr_kernel<<<N, 64, 0, stream>>>(row_ptr, col_src, col_attr, al_s, al_d, xh, b2, we_dot, 1, feat2, N);
    // pool + linear (hierarchical: LDS bins then ~2 global atomics per block)
    pool_kernel<<<512, 256, 0, stream>>>(feat2, Wlin, batch, pool_sum, pool_cnt, N);
    final_kernel<<<1, 64, 0, stream>>>(pool_sum, pool_cnt, blin, out);
}

// Round 3
// 373.780 us; speedup vs baseline: 2.5490x; 1.5636x over previous
//
#include <hip/hip_runtime.h>
#include <hip/hip_bf16.h>
#include <math.h>

#define LRELU(a) ((a) > 0.f ? (a) : 0.2f * (a))

// ---------------- CSR build ----------------

__global__ void hist_kernel(const int* __restrict__ dst, const float* __restrict__ eattr,
                            int* __restrict__ cnt_i, float* __restrict__ attr_sum, int E) {
    int e = blockIdx.x * blockDim.x + threadIdx.x;
    if (e < E) {
        int d = dst[e];
        atomicAdd(&cnt_i[d], 1);
        atomicAdd(&attr_sum[d], eattr[e]);
    }
}

// 3-phase parallel exclusive scan over (cnt_i[n]+1), replacing the single-block scan.

__global__ __launch_bounds__(256) void scan_phase1(const int* __restrict__ cnt_i,
                                                   int* __restrict__ block_sum, int N) {
    int t = threadIdx.x;
    int n = blockIdx.x * 256 + t;
    int v = (n < N) ? cnt_i[n] + 1 : 0;  // +1 self loop
#pragma unroll
    for (int m = 32; m >= 1; m >>= 1) v += __shfl_xor(v, m);
    __shared__ int ws[4];
    if ((t & 63) == 0) ws[t >> 6] = v;
    __syncthreads();
    if (t == 0) block_sum[blockIdx.x] = ws[0] + ws[1] + ws[2] + ws[3];
}

__global__ __launch_bounds__(1024) void scan_phase2(const int* __restrict__ block_sum,
                                                    int* __restrict__ block_off,
                                                    int* __restrict__ row_ptr, int B, int N) {
    __shared__ int s[1024];
    int t = threadIdx.x;
    int v = (t < B) ? block_sum[t] : 0;
    s[t] = v;
    __syncthreads();
    for (int off = 1; off < 1024; off <<= 1) {
        int u = (t >= off) ? s[t - off] : 0;
        __syncthreads();
        s[t] += u;
        __syncthreads();
    }
    if (t < B) block_off[t] = s[t] - v;       // exclusive offset for block t
    if (t == 1023) row_ptr[N] = s[1023];      // total = E + N
}

__global__ __launch_bounds__(256) void scan_phase3(const int* __restrict__ cnt_i,
                                                   const float* __restrict__ attr_sum,
                                                   const int* __restrict__ block_off,
                                                   int* __restrict__ row_ptr, int* __restrict__ cursor,
                                                   int* __restrict__ col_src, float* __restrict__ col_attr, int N) {
    int t = threadIdx.x;
    int lane = t & 63;
    int n = blockIdx.x * 256 + t;
    int c = (n < N) ? cnt_i[n] + 1 : 0;
    // inclusive scan within wave
    int v = c;
#pragma unroll
    for (int m = 1; m < 64; m <<= 1) {
        int u = __shfl_up(v, m);
        if (lane >= m) v += u;
    }
    __shared__ int wsum[4];
    if (lane == 63) wsum[t >> 6] = v;
    __syncthreads();
    int w = t >> 6;
    int wadd = 0;
#pragma unroll
    for (int i = 0; i < 3; i++) wadd += (i < w) ? wsum[i] : 0;
    int base = block_off[blockIdx.x] + wadd + v - c;  // exclusive position
    if (n < N) {
        row_ptr[n] = base;
        float la = attr_sum[n] / fmaxf((float)(c - 1), 1.f);  // fill_value='mean' self-loop attr
        col_src[base] = n;                                     // self loop first in row
        col_attr[base] = la;
        cursor[n] = base + 1;
    }
}

__global__ void scatter_kernel(const int* __restrict__ src, const int* __restrict__ dst,
                               const float* __restrict__ eattr, int* __restrict__ cursor,
                               int* __restrict__ col_src, float* __restrict__ col_attr, int E) {
    int e = blockIdx.x * blockDim.x + threadIdx.x;
    if (e < E) {
        int d = dst[e];
        int pos = atomicAdd(&cursor[d], 1);
        col_src[pos] = src[e];
        col_attr[pos] = eattr[e];
    }
}

// ---------------- per-layer node projection: xh = feat @ W, al_s/al_d dots ----------------

template<int FIN>
__global__ __launch_bounds__(128) void node_proj_kernel(
        const float* __restrict__ feat, const float* __restrict__ W,
        const float* __restrict__ as_, const float* __restrict__ ad_,
        float* __restrict__ xh, float* __restrict__ al_s, float* __restrict__ al_d, int N) {
    __shared__ float sf[FIN];
    int n = blockIdx.x;
    if (n >= N) return;
    int j = threadIdx.x;  // 0..127  (h = j>>6, c = j&63)
    if (j < FIN) sf[j] = feat[(size_t)n * FIN + j];
    __syncthreads();
    float acc = 0.f;
#pragma unroll
    for (int k = 0; k < FIN; k++) acc += sf[k] * W[k * 128 + j];
    xh[(size_t)n * 128 + j] = acc;
    float vs = acc * as_[j];
    float vd = acc * ad_[j];
#pragma unroll
    for (int m = 32; m >= 1; m >>= 1) {
        vs += __shfl_xor(vs, m);
        vd += __shfl_xor(vd, m);
    }
    if ((j & 63) == 0) {
        int h = j >> 6;
        al_s[n * 2 + h] = vs;
        al_d[n * 2 + h] = vd;
    }
}

// al_e[e,h] = eattr[e] * dot(We[h,:], ae[h,:])  -> precompute the 4 scalars (2 layers x 2 heads)
__global__ __launch_bounds__(256) void wedot_kernel(const float* __restrict__ We1, const float* __restrict__ ae1,
                                                    const float* __restrict__ We2, const float* __restrict__ ae2,
                                                    float* __restrict__ we_dot) {
    int t = threadIdx.x;
    int g = t >> 6, lane = t & 63;          // g = layer*2 + h
    const float* We = (g & 2) ? We2 : We1;
    const float* ae = (g & 2) ? ae2 : ae1;
    int h = g & 1;
    float v = We[h * 64 + lane] * ae[h * 64 + lane];
#pragma unroll
    for (int m = 32; m >= 1; m >>= 1) v += __shfl_xor(v, m);
    if (lane == 0) we_dot[g] = v;
}

// ---------------- edge aggregation: segment softmax + weighted sum, one wave per dst ----------------

__global__ __launch_bounds__(64) void edge_aggr_kernel(
        const int* __restrict__ row_ptr, const int* __restrict__ col_src, const float* __restrict__ col_attr,
        const float* __restrict__ al_s, const float* __restrict__ al_d, const float* __restrict__ xh,
        const float* __restrict__ bias, const float* __restrict__ we_dot, int layer,
        float* __restrict__ out, int N) {
    __shared__ float s_ex0[64], s_ex1[64];
    __shared__ int s_src[64];
    int n = blockIdx.x;
    if (n >= N) return;
    int lane = threadIdx.x;
    int start = row_ptr[n], end = row_ptr[n + 1];
    float we0 = we_dot[layer * 2], we1 = we_dot[layer * 2 + 1];
    float ald0 = al_d[2 * n], ald1 = al_d[2 * n + 1];

    // pass 1: per-head max over incoming edges (segment_max)
    float m0 = -INFINITY, m1 = -INFINITY;
    for (int i = start + lane; i < end; i += 64) {
        int sc = col_src[i];
        float at = col_attr[i];
        float a0 = al_s[2 * sc] + ald0 + we0 * at;
        float a1 = al_s[2 * sc + 1] + ald1 + we1 * at;
        a0 = LRELU(a0); a1 = LRELU(a1);
        m0 = fmaxf(m0, a0); m1 = fmaxf(m1, a1);
    }
#pragma unroll
    for (int m = 32; m >= 1; m >>= 1) {
        m0 = fmaxf(m0, __shfl_xor(m0, m));
        m1 = fmaxf(m1, __shfl_xor(m1, m));
    }

    // pass 2: unnormalized accumulation (att = ex/den is linear -> normalize at the end)
    float den0 = 0.f, den1 = 0.f, acc0 = 0.f, acc1 = 0.f;
    for (int cs = start; cs < end; cs += 64) {
        int i = cs + lane;
        float e0 = 0.f, e1 = 0.f;
        int sc = 0;
        if (i < end) {
            sc = col_src[i];
            float at = col_attr[i];
            float a0 = al_s[2 * sc] + ald0 + we0 * at;
            float a1 = al_s[2 * sc + 1] + ald1 + we1 * at;
            a0 = LRELU(a0); a1 = LRELU(a1);
            e0 = expf(a0 - m0);
            e1 = expf(a1 - m1);
        }
        den0 += e0; den1 += e1;
        s_ex0[lane] = e0; s_ex1[lane] = e1; s_src[lane] = sc;
        __syncthreads();
        int cnt = min(64, end - cs);
        for (int j = 0; j < cnt; j++) {
            float w0 = s_ex0[j], w1 = s_ex1[j];
            size_t sj = (size_t)s_src[j] * 128;
            acc0 += w0 * xh[sj + lane];        // head 0 channels
            acc1 += w1 * xh[sj + 64 + lane];   // head 1 channels
        }
        __syncthreads();
    }
#pragma unroll
    for (int m = 32; m >= 1; m >>= 1) {
        den0 += __shfl_xor(den0, m);
        den1 += __shfl_xor(den1, m);
    }
    float o = 0.5f * (acc0 / (den0 + 1e-16f) + acc1 / (den1 + 1e-16f)) + bias[lane];
    out[(size_t)n * 64 + lane] = fmaxf(o, 0.f);  // relu fused
}

// ---------------- pooling: hierarchical (LDS bins -> few global atomics) ----------------

__global__ __launch_bounds__(256) void pool_kernel(const float* __restrict__ feat,
                                                   const float* __restrict__ Wlin, const int* __restrict__ batch,
                                                   float* __restrict__ pool_sum, int* __restrict__ pool_cnt, int N) {
    __shared__ float s_sum[64];
    __shared__ int s_cnt[64];
    int t = threadIdx.x;
    if (t < 64) { s_sum[t] = 0.f; s_cnt[t] = 0; }
    __syncthreads();

    int nblk = gridDim.x;
    int chunk = (N + nblk - 1) / nblk;
    int lo = blockIdx.x * chunk;
    int hi = min(lo + chunk, N);
    int lane = t & 63;
    float wl = Wlin[lane];

    for (int node = lo + (t >> 6); node < hi; node += 4) {
        float v = feat[(size_t)node * 64 + lane] * wl;
#pragma unroll
        for (int m = 32; m >= 1; m >>= 1) v += __shfl_xor(v, m);
        if (lane == 0) {
            int g = batch[node];
            atomicAdd(&s_sum[g], v);
            atomicAdd(&s_cnt[g], 1);
        }
    }
    __syncthreads();
    if (t < 64 && s_cnt[t] > 0) {
        atomicAdd(&pool_sum[t], s_sum[t]);
        atomicAdd(&pool_cnt[t], s_cnt[t]);
    }
}

__global__ void final_kernel(const float* __restrict__ pool_sum, const int* __restrict__ pool_cnt,
                             const float* __restrict__ blin, float* __restrict__ out) {
    int g = threadIdx.x;
    if (g < 64) out[g] = pool_sum[g] / fmaxf((float)pool_cnt[g], 1.f) + blin[0];
}

// ---------------- launch ----------------

extern "C" void kernel_launch(void* const* d_in, const int* in_sizes, int n_in,
                              void* d_out, int out_size, void* d_ws, size_t ws_size,
                              hipStream_t stream) {
    const float* x     = (const float*)d_in[0];
    const int*   ei    = (const int*)d_in[1];
    const float* eattr = (const float*)d_in[2];
    const int*   batch = (const int*)d_in[3];
    const float* W1  = (const float*)d_in[4];
    const float* as1 = (const float*)d_in[5];
    const float* ad1 = (const float*)d_in[6];
    const float* We1 = (const float*)d_in[7];
    const float* ae1 = (const float*)d_in[8];
    const float* b1  = (const float*)d_in[9];
    const float* W2  = (const float*)d_in[10];
    const float* as2 = (const float*)d_in[11];
    const float* ad2 = (const float*)d_in[12];
    const float* We2 = (const float*)d_in[13];
    const float* ae2 = (const float*)d_in[14];
    const float* b2  = (const float*)d_in[15];
    const float* Wlin = (const float*)d_in[16];
    const float* blin = (const float*)d_in[17];
    float* out = (float*)d_out;

    int N = in_sizes[0] / 5;
    int E = in_sizes[1] / 2;
    size_t EP = (size_t)E + N;
    const int* src0 = ei;
    const int* dst0 = ei + E;
    int B = (N + 255) / 256;   // blocks for node-chunked scan (must be <= 1024)

    char* ws = (char*)d_ws;
    size_t off = 0;
    auto alloc = [&](size_t bytes) {
        void* p = ws + off;
        off = (off + bytes + 255) & ~(size_t)255;
        return p;
    };
    int*   cnt_i    = (int*)  alloc((size_t)N * 4);
    float* attr_sum = (float*)alloc((size_t)N * 4);
    int*   row_ptr  = (int*)  alloc((size_t)(N + 1) * 4);
    int*   cursor   = (int*)  alloc((size_t)N * 4);
    int*   col_src  = (int*)  alloc(EP * 4);
    float* col_attr = (float*)alloc(EP * 4);
    int*   block_sum= (int*)  alloc((size_t)1024 * 4);
    int*   block_off= (int*)  alloc((size_t)1024 * 4);
    float* al_s     = (float*)alloc((size_t)N * 2 * 4);
    float* al_d     = (float*)alloc((size_t)N * 2 * 4);
    float* xh       = (float*)alloc((size_t)N * 128 * 4);
    float* feat1    = (float*)alloc((size_t)N * 64 * 4);
    float* feat2    = (float*)alloc((size_t)N * 64 * 4);
    float* we_dot   = (float*)alloc(4 * 4);
    float* pool_sum = (float*)alloc(64 * 4);
    int*   pool_cnt = (int*)  alloc(64 * 4);

    hipMemsetAsync(cnt_i, 0, (size_t)N * 4, stream);
    hipMemsetAsync(attr_sum, 0, (size_t)N * 4, stream);
    hipMemsetAsync(block_sum, 0, (size_t)1024 * 4, stream);
    hipMemsetAsync(pool_sum, 0, 64 * 4, stream);
    hipMemsetAsync(pool_cnt, 0, 64 * 4, stream);

    hist_kernel<<<(E + 255) / 256, 256, 0, stream>>>(dst0, eattr, cnt_i, attr_sum, E);
    scan_phase1<<<B, 256, 0, stream>>>(cnt_i, block_sum, N);
    scan_phase2<<<1, 1024, 0, stream>>>(block_sum, block_off, row_ptr, B, N);
    scan_phase3<<<B, 256, 0, stream>>>(cnt_i, attr_sum, block_off, row_ptr, cursor, col_src, col_attr, N);
    scatter_kernel<<<(E + 255) / 256, 256, 0, stream>>>(src0, dst0, eattr, cursor, col_src, col_attr, E);
    wedot_kernel<<<1, 256, 0, stream>>>(We1, ae1, We2, ae2, we_dot);

    // layer 1
    node_proj_kernel<5><<<N, 128, 0, stream>>>(x, W1, as1, ad1, xh, al_s, al_d, N);
    edge_aggr_kernel<<<N, 64, 0, stream>>>(row_ptr, col_src, col_attr, al_s, al_d, xh, b1, we_dot, 0, feat1, N);
    // layer 2
    node_proj_kernel<64><<<N, 128, 0, stream>>>(feat1, W2, as2, ad2, xh, al_s, al_d, N);
    edge_aggr_kernel<<<N, 64, 0, stream>>>(row_ptr, col_src, col_attr, al_s, al_d, xh, b2, we_dot, 1, feat2, N);
    // pool + linear (hierarchical: LDS bins then ~2 global atomics per block)
    pool_kernel<<<512, 256, 0, stream>>>(feat2, Wlin, batch, pool_sum, pool_cnt, N);
    final_kernel<<<1, 64, 0, stream>>>(pool_sum, pool_cnt, blin, out);
}

// Round 5
// 341.739 us; speedup vs baseline: 2.7880x; 1.0938x over previous
//
#include <hip/hip_runtime.h>
#include <hip/hip_bf16.h>
#include <math.h>

#define LRELU(a) ((a) > 0.f ? (a) : 0.2f * (a))

#define FIX_SCALE 67108864.0f          // 2^26 fixed-point for attr sums
#define FIX_INV   (1.0f / 67108864.0f)
#define CNT_SHIFT 40
#define SUM_MASK  0xFFFFFFFFFFULL

// ---------------- CSR build ----------------
// hist[d] packs {count << 40 | sum(attr * 2^26)} in one u64 atomic per edge.

__global__ void hist_kernel(const int* __restrict__ dst, const float* __restrict__ eattr,
                            unsigned long long* __restrict__ hist, int E) {
    int e = blockIdx.x * blockDim.x + threadIdx.x;
    if (e < E) {
        int d = dst[e];
        unsigned long long v = (1ULL << CNT_SHIFT) |
                               (unsigned long long)(eattr[e] * FIX_SCALE + 0.5f);
        atomicAdd(&hist[d], v);
    }
}

// 3-phase parallel exclusive scan over (cnt[n]+1).

__global__ __launch_bounds__(256) void scan_phase1(const unsigned long long* __restrict__ hist,
                                                   int* __restrict__ block_sum, int N) {
    int t = threadIdx.x;
    int n = blockIdx.x * 256 + t;
    int v = (n < N) ? (int)(hist[n] >> CNT_SHIFT) + 1 : 0;  // +1 self loop
#pragma unroll
    for (int m = 32; m >= 1; m >>= 1) v += __shfl_xor(v, m);
    __shared__ int ws[4];
    if ((t & 63) == 0) ws[t >> 6] = v;
    __syncthreads();
    if (t == 0) block_sum[blockIdx.x] = ws[0] + ws[1] + ws[2] + ws[3];
}

__global__ __launch_bounds__(1024) void scan_phase2(const int* __restrict__ block_sum,
                                                    int* __restrict__ block_off,
                                                    int* __restrict__ row_ptr, int B, int N) {
    __shared__ int s[1024];
    int t = threadIdx.x;
    int v = (t < B) ? block_sum[t] : 0;
    s[t] = v;
    __syncthreads();
    for (int off = 1; off < 1024; off <<= 1) {
        int u = (t >= off) ? s[t - off] : 0;
        __syncthreads();
        s[t] += u;
        __syncthreads();
    }
    if (t < B) block_off[t] = s[t] - v;       // exclusive offset for block t
    if (t == 1023) row_ptr[N] = s[1023];      // total = E + N
}

__global__ __launch_bounds__(256) void scan_phase3(const unsigned long long* __restrict__ hist,
                                                   const int* __restrict__ block_off,
                                                   int* __restrict__ row_ptr, int* __restrict__ cursor,
                                                   int2* __restrict__ col, int N) {
    int t = threadIdx.x;
    int lane = t & 63;
    int n = blockIdx.x * 256 + t;
    unsigned long long hv = (n < N) ? hist[n] : 0ULL;
    int c = (n < N) ? (int)(hv >> CNT_SHIFT) + 1 : 0;
    // inclusive scan within wave
    int v = c;
#pragma unroll
    for (int m = 1; m < 64; m <<= 1) {
        int u = __shfl_up(v, m);
        if (lane >= m) v += u;
    }
    __shared__ int wsum[4];
    if (lane == 63) wsum[t >> 6] = v;
    __syncthreads();
    int w = t >> 6;
    int wadd = 0;
#pragma unroll
    for (int i = 0; i < 3; i++) wadd += (i < w) ? wsum[i] : 0;
    int base = block_off[blockIdx.x] + wadd + v - c;  // exclusive position
    if (n < N) {
        row_ptr[n] = base;
        float asum = (float)(hv & SUM_MASK) * FIX_INV;
        float la = asum / fmaxf((float)(c - 1), 1.f);  // fill_value='mean' self-loop attr
        col[base] = make_int2(n, __float_as_int(la));   // self loop first in row
        cursor[n] = base + 1;
    }
}

__global__ void scatter_kernel(const int* __restrict__ src, const int* __restrict__ dst,
                               const float* __restrict__ eattr, int* __restrict__ cursor,
                               int2* __restrict__ col, int E) {
    int e = blockIdx.x * blockDim.x + threadIdx.x;
    if (e < E) {
        int d = dst[e];
        int pos = atomicAdd(&cursor[d], 1);
        col[pos] = make_int2(src[e], __float_as_int(eattr[e]));
    }
}

// ---------------- per-layer node projection: xh = feat @ W, al_s/al_d dots ----------------

template<int FIN>
__global__ __launch_bounds__(128) void node_proj_kernel(
        const float* __restrict__ feat, const float* __restrict__ W,
        const float* __restrict__ as_, const float* __restrict__ ad_,
        float* __restrict__ xh, float* __restrict__ al_s, float* __restrict__ al_d, int N) {
    __shared__ float sf[FIN];
    int n = blockIdx.x;
    if (n >= N) return;
    int j = threadIdx.x;  // 0..127  (h = j>>6, c = j&63)
    if (j < FIN) sf[j] = feat[(size_t)n * FIN + j];
    __syncthreads();
    float acc = 0.f;
#pragma unroll
    for (int k = 0; k < FIN; k++) acc += sf[k] * W[k * 128 + j];
    xh[(size_t)n * 128 + j] = acc;
    float vs = acc * as_[j];
    float vd = acc * ad_[j];
#pragma unroll
    for (int m = 32; m >= 1; m >>= 1) {
        vs += __shfl_xor(vs, m);
        vd += __shfl_xor(vd, m);
    }
    if ((j & 63) == 0) {
        int h = j >> 6;
        al_s[n * 2 + h] = vs;
        al_d[n * 2 + h] = vd;
    }
}

// al_e[e,h] = eattr[e] * dot(We[h,:], ae[h,:])  -> precompute the 4 scalars (2 layers x 2 heads)
__global__ __launch_bounds__(256) void wedot_kernel(const float* __restrict__ We1, const float* __restrict__ ae1,
                                                    const float* __restrict__ We2, const float* __restrict__ ae2,
                                                    float* __restrict__ we_dot) {
    int t = threadIdx.x;
    int g = t >> 6, lane = t & 63;          // g = layer*2 + h
    const float* We = (g & 2) ? We2 : We1;
    const float* ae = (g & 2) ? ae2 : ae1;
    int h = g & 1;
    float v = We[h * 64 + lane] * ae[h * 64 + lane];
#pragma unroll
    for (int m = 32; m >= 1; m >>= 1) v += __shfl_xor(v, m);
    if (lane == 0) we_dot[g] = v;
}

// ---------------- edge aggregation: segment softmax + weighted sum, one wave per dst ----------------

__global__ __launch_bounds__(64) void edge_aggr_kernel(
        const int* __restrict__ row_ptr, const int2* __restrict__ col,
        const float2* __restrict__ al_s, const float2* __restrict__ al_d,
        const float* __restrict__ xh,
        const float* __restrict__ bias, const float* __restrict__ we_dot, int layer,
        float* __restrict__ out, int N) {
    __shared__ float s_ex0[64], s_ex1[64];
    __shared__ int s_src[64];
    int n = blockIdx.x;
    if (n >= N) return;
    int lane = threadIdx.x;
    int start = row_ptr[n], end = row_ptr[n + 1];
    int cnt = end - start;
    float we0 = we_dot[layer * 2], we1 = we_dot[layer * 2 + 1];
    float2 ald = al_d[n];

    if (cnt <= 64) {
        // ---- fast path: single chunk, alpha computed once, float2 row gather ----
        float a0 = -INFINITY, a1 = -INFINITY;
        int sc = 0;
        if (lane < cnt) {
            int2 ce = col[start + lane];
            sc = ce.x;
            float at = __int_as_float(ce.y);
            float2 als = al_s[sc];
            a0 = als.x + ald.x + we0 * at;
            a1 = als.y + ald.y + we1 * at;
            a0 = LRELU(a0); a1 = LRELU(a1);
        }
        float m0 = a0, m1 = a1;
#pragma unroll
        for (int m = 32; m >= 1; m >>= 1) {
            m0 = fmaxf(m0, __shfl_xor(m0, m));
            m1 = fmaxf(m1, __shfl_xor(m1, m));
        }
        float e0 = 0.f, e1 = 0.f;
        if (lane < cnt) {
            e0 = __expf(a0 - m0);
            e1 = __expf(a1 - m1);
        }
        float den0 = e0, den1 = e1;
        s_ex0[lane] = e0; s_ex1[lane] = e1; s_src[lane] = sc;
        __syncthreads();

        // lane holds float2 = channels {2*lane, 2*lane+1}; lanes<32 head0, lanes>=32 head1
        const float* s_w = (lane < 32) ? s_ex0 : s_ex1;
        const float2* xh2 = (const float2*)xh;
        float accx = 0.f, accy = 0.f;
        for (int j = 0; j < cnt; j++) {
            float w = s_w[j];
            float2 v = xh2[(size_t)s_src[j] * 64 + lane];
            accx += w * v.x;
            accy += w * v.y;
        }
#pragma unroll
        for (int m = 32; m >= 1; m >>= 1) {
            den0 += __shfl_xor(den0, m);
            den1 += __shfl_xor(den1, m);
        }
        float inv0 = 1.f / (den0 + 1e-16f), inv1 = 1.f / (den1 + 1e-16f);
        float px = __shfl_xor(accx, 32);   // partner head's partials, same channels
        float py = __shfl_xor(accy, 32);
        if (lane < 32) {
            float2 bv = ((const float2*)bias)[lane];
            float ox = 0.5f * (accx * inv0 + px * inv1) + bv.x;
            float oy = 0.5f * (accy * inv0 + py * inv1) + bv.y;
            ((float2*)out)[(size_t)n * 32 + lane] = make_float2(fmaxf(ox, 0.f), fmaxf(oy, 0.f));
        }
        return;
    }

    // ---- general path (cnt > 64, statistically never at mean degree 17) ----
    float m0 = -INFINITY, m1 = -INFINITY;
    for (int i = start + lane; i < end; i += 64) {
        int2 ce = col[i];
        float at = __int_as_float(ce.y);
        float2 als = al_s[ce.x];
        float a0 = als.x + ald.x + we0 * at;
        float a1 = als.y + ald.y + we1 * at;
        a0 = LRELU(a0); a1 = LRELU(a1);
        m0 = fmaxf(m0, a0); m1 = fmaxf(m1, a1);
    }
#pragma unroll
    for (int m = 32; m >= 1; m >>= 1) {
        m0 = fmaxf(m0, __shfl_xor(m0, m));
        m1 = fmaxf(m1, __shfl_xor(m1, m));
    }
    float den0 = 0.f, den1 = 0.f, acc0 = 0.f, acc1 = 0.f;
    for (int cs = start; cs < end; cs += 64) {
        int i = cs + lane;
        float e0 = 0.f, e1 = 0.f;
        int sc = 0;
        if (i < end) {
            int2 ce = col[i];
            sc = ce.x;
            float at = __int_as_float(ce.y);
            float2 als = al_s[sc];
            float a0 = als.x + ald.x + we0 * at;
            float a1 = als.y + ald.y + we1 * at;
            a0 = LRELU(a0); a1 = LRELU(a1);
            e0 = __expf(a0 - m0);
            e1 = __expf(a1 - m1);
        }
        den0 += e0; den1 += e1;
        s_ex0[lane] = e0; s_ex1[lane] = e1; s_src[lane] = sc;
        __syncthreads();
        int c2 = min(64, end - cs);
        for (int j = 0; j < c2; j++) {
            float w0 = s_ex0[j], w1 = s_ex1[j];
            size_t sj = (size_t)s_src[j] * 128;
            acc0 += w0 * xh[sj + lane];
            acc1 += w1 * xh[sj + 64 + lane];
        }
        __syncthreads();
    }
#pragma unroll
    for (int m = 32; m >= 1; m >>= 1) {
        den0 += __shfl_xor(den0, m);
        den1 += __shfl_xor(den1, m);
    }
    float o = 0.5f * (acc0 / (den0 + 1e-16f) + acc1 / (den1 + 1e-16f)) + bias[lane];
    out[(size_t)n * 64 + lane] = fmaxf(o, 0.f);
}

// ---------------- pooling: hierarchical (LDS bins -> few global atomics) ----------------

__global__ __launch_bounds__(256) void pool_kernel(const float* __restrict__ feat,
                                                   const float* __restrict__ Wlin, const int* __restrict__ batch,
                                                   float* __restrict__ pool_sum, int* __restrict__ pool_cnt, int N) {
    __shared__ float s_sum[64];
    __shared__ int s_cnt[64];
    int t = threadIdx.x;
    if (t < 64) { s_sum[t] = 0.f; s_cnt[t] = 0; }
    __syncthreads();

    int nblk = gridDim.x;
    int chunk = (N + nblk - 1) / nblk;
    int lo = blockIdx.x * chunk;
    int hi = min(lo + chunk, N);
    int lane = t & 63;
    float wl = Wlin[lane];

    for (int node = lo + (t >> 6); node < hi; node += 4) {
        float v = feat[(size_t)node * 64 + lane] * wl;
#pragma unroll
        for (int m = 32; m >= 1; m >>= 1) v += __shfl_xor(v, m);
        if (lane == 0) {
            int g = batch[node];
            atomicAdd(&s_sum[g], v);
            atomicAdd(&s_cnt[g], 1);
        }
    }
    __syncthreads();
    if (t < 64 && s_cnt[t] > 0) {
        atomicAdd(&pool_sum[t], s_sum[t]);
        atomicAdd(&pool_cnt[t], s_cnt[t]);
    }
}

__global__ void final_kernel(const float* __restrict__ pool_sum, const int* __restrict__ pool_cnt,
                             const float* __restrict__ blin, float* __restrict__ out) {
    int g = threadIdx.x;
    if (g < 64) out[g] = pool_sum[g] / fmaxf((float)pool_cnt[g], 1.f) + blin[0];
}

// ---------------- launch ----------------

extern "C" void kernel_launch(void* const* d_in, const int* in_sizes, int n_in,
                              void* d_out, int out_size, void* d_ws, size_t ws_size,
                              hipStream_t stream) {
    const float* x     = (const float*)d_in[0];
    const int*   ei    = (const int*)d_in[1];
    const float* eattr = (const float*)d_in[2];
    const int*   batch = (const int*)d_in[3];
    const float* W1  = (const float*)d_in[4];
    const float* as1 = (const float*)d_in[5];
    const float* ad1 = (const float*)d_in[6];
    const float* We1 = (const float*)d_in[7];
    const float* ae1 = (const float*)d_in[8];
    const float* b1  = (const float*)d_in[9];
    const float* W2  = (const float*)d_in[10];
    const float* as2 = (const float*)d_in[11];
    const float* ad2 = (const float*)d_in[12];
    const float* We2 = (const float*)d_in[13];
    const float* ae2 = (const float*)d_in[14];
    const float* b2  = (const float*)d_in[15];
    const float* Wlin = (const float*)d_in[16];
    const float* blin = (const float*)d_in[17];
    float* out = (float*)d_out;

    int N = in_sizes[0] / 5;
    int E = in_sizes[1] / 2;
    size_t EP = (size_t)E + N;
    const int* src0 = ei;
    const int* dst0 = ei + E;
    int B = (N + 255) / 256;   // blocks for node-chunked scan (must be <= 1024)

    char* ws = (char*)d_ws;
    size_t off = 0;
    auto alloc = [&](size_t bytes) {
        void* p = ws + off;
        off = (off + bytes + 255) & ~(size_t)255;
        return p;
    };
    unsigned long long* hist = (unsigned long long*)alloc((size_t)N * 8);
    int*   row_ptr  = (int*)  alloc((size_t)(N + 1) * 4);
    int*   cursor   = (int*)  alloc((size_t)N * 4);
    int2*  col      = (int2*) alloc(EP * 8);
    int*   block_sum= (int*)  alloc((size_t)1024 * 4);
    int*   block_off= (int*)  alloc((size_t)1024 * 4);
    float* al_s     = (float*)alloc((size_t)N * 2 * 4);
    float* al_d     = (float*)alloc((size_t)N * 2 * 4);
    float* xh       = (float*)alloc((size_t)N * 128 * 4);
    float* feat1    = (float*)alloc((size_t)N * 64 * 4);
    float* feat2    = (float*)alloc((size_t)N * 64 * 4);
    float* we_dot   = (float*)alloc(4 * 4);
    float* pool_sum = (float*)alloc(64 * 4);
    int*   pool_cnt = (int*)  alloc(64 * 4);

    hipMemsetAsync(hist, 0, (size_t)N * 8, stream);
    hipMemsetAsync(block_sum, 0, (size_t)1024 * 4, stream);
    hipMemsetAsync(pool_sum, 0, 64 * 4, stream);
    hipMemsetAsync(pool_cnt, 0, 64 * 4, stream);

    hist_kernel<<<(E + 255) / 256, 256, 0, stream>>>(dst0, eattr, hist, E);
    scan_phase1<<<B, 256, 0, stream>>>(hist, block_sum, N);
    scan_phase2<<<1, 1024, 0, stream>>>(block_sum, block_off, row_ptr, B, N);
    scan_phase3<<<B, 256, 0, stream>>>(hist, block_off, row_ptr, cursor, col, N);
    scatter_kernel<<<(E + 255) / 256, 256, 0, stream>>>(src0, dst0, eattr, cursor, col, E);
    wedot_kernel<<<1, 256, 0, stream>>>(We1, ae1, We2, ae2, we_dot);

    // layer 1
    node_proj_kernel<5><<<N, 128, 0, stream>>>(x, W1, as1, ad1, xh, al_s, al_d, N);
    edge_aggr_kernel<<<N, 64, 0, stream>>>(row_ptr, col, (const float2*)al_s, (const float2*)al_d,
                                           xh, b1, we_dot, 0, feat1, N);
    // layer 2
    node_proj_kernel<64><<<N, 128, 0, stream>>>(feat1, W2, as2, ad2, xh, al_s, al_d, N);
    edge_aggr_kernel<<<N, 64, 0, stream>>>(row_ptr, col, (const float2*)al_s, (const float2*)al_d,
                                           xh, b2, we_dot, 1, feat2, N);
    // pool + linear (hierarchical: LDS bins then ~2 global atomics per block)
    pool_kernel<<<512, 256, 0, stream>>>(feat2, Wlin, batch, pool_sum, pool_cnt, N);
    final_kernel<<<1, 64, 0, stream>>>(pool_sum, pool_cnt, blin, out);
}

// Round 6
// 281.145 us; speedup vs baseline: 3.3889x; 1.2155x over previous
//
#include <hip/hip_runtime.h>
#include <hip/hip_bf16.h>
#include <math.h>

typedef unsigned int u32;

#define LRELU(a) ((a) > 0.f ? (a) : 0.2f * (a))

#define FIX_SCALE 67108864.0f          // 2^26 fixed-point for attr sums
#define FIX_INV   (1.0f / 67108864.0f)
#define CNT_SHIFT 40
#define SUM_MASK  0xFFFFFFFFFFULL

// round-to-nearest-even f32 -> bf16 bits
__device__ __forceinline__ u32 f2bf(float f) {
    u32 u = __float_as_uint(f);
    return (u + 0x7fffu + ((u >> 16) & 1u)) >> 16;
}

// ---------------- CSR build ----------------
// hist[d] packs {count << 40 | sum(attr * 2^26)} in one u64 atomic per edge.

__global__ void hist_kernel(const int* __restrict__ dst, const float* __restrict__ eattr,
                            unsigned long long* __restrict__ hist, int E) {
    int e = blockIdx.x * blockDim.x + threadIdx.x;
    if (e < E) {
        int d = dst[e];
        unsigned long long v = (1ULL << CNT_SHIFT) |
                               (unsigned long long)(eattr[e] * FIX_SCALE + 0.5f);
        atomicAdd(&hist[d], v);
    }
}

// 3-phase parallel exclusive scan over (cnt[n]+1).

__global__ __launch_bounds__(256) void scan_phase1(const unsigned long long* __restrict__ hist,
                                                   int* __restrict__ block_sum, int N) {
    int t = threadIdx.x;
    int n = blockIdx.x * 256 + t;
    int v = (n < N) ? (int)(hist[n] >> CNT_SHIFT) + 1 : 0;  // +1 self loop
#pragma unroll
    for (int m = 32; m >= 1; m >>= 1) v += __shfl_xor(v, m);
    __shared__ int ws[4];
    if ((t & 63) == 0) ws[t >> 6] = v;
    __syncthreads();
    if (t == 0) block_sum[blockIdx.x] = ws[0] + ws[1] + ws[2] + ws[3];
}

__global__ __launch_bounds__(1024) void scan_phase2(const int* __restrict__ block_sum,
                                                    int* __restrict__ block_off,
                                                    int* __restrict__ row_ptr, int B, int N) {
    __shared__ int s[1024];
    int t = threadIdx.x;
    int v = (t < B) ? block_sum[t] : 0;
    s[t] = v;
    __syncthreads();
    for (int off = 1; off < 1024; off <<= 1) {
        int u = (t >= off) ? s[t - off] : 0;
        __syncthreads();
        s[t] += u;
        __syncthreads();
    }
    if (t < B) block_off[t] = s[t] - v;       // exclusive offset for block t
    if (t == 1023) row_ptr[N] = s[1023];      // total = E + N
}

__global__ __launch_bounds__(256) void scan_phase3(const unsigned long long* __restrict__ hist,
                                                   const int* __restrict__ block_off,
                                                   int* __restrict__ row_ptr, int* __restrict__ cursor,
                                                   int2* __restrict__ col, int N) {
    int t = threadIdx.x;
    int lane = t & 63;
    int n = blockIdx.x * 256 + t;
    unsigned long long hv = (n < N) ? hist[n] : 0ULL;
    int c = (n < N) ? (int)(hv >> CNT_SHIFT) + 1 : 0;
    // inclusive scan within wave
    int v = c;
#pragma unroll
    for (int m = 1; m < 64; m <<= 1) {
        int u = __shfl_up(v, m);
        if (lane >= m) v += u;
    }
    __shared__ int wsum[4];
    if (lane == 63) wsum[t >> 6] = v;
    __syncthreads();
    int w = t >> 6;
    int wadd = 0;
#pragma unroll
    for (int i = 0; i < 3; i++) wadd += (i < w) ? wsum[i] : 0;
    int base = block_off[blockIdx.x] + wadd + v - c;  // exclusive position
    if (n < N) {
        row_ptr[n] = base;
        float asum = (float)(hv & SUM_MASK) * FIX_INV;
        float la = asum / fmaxf((float)(c - 1), 1.f);  // fill_value='mean' self-loop attr
        col[base] = make_int2(n, __float_as_int(la));   // self loop first in row
        cursor[n] = base + 1;
    }
}

__global__ void scatter_kernel(const int* __restrict__ src, const int* __restrict__ dst,
                               const float* __restrict__ eattr, int* __restrict__ cursor,
                               int2* __restrict__ col, int E) {
    int e = blockIdx.x * blockDim.x + threadIdx.x;
    if (e < E) {
        int d = dst[e];
        int pos = atomicAdd(&cursor[d], 1);
        col[pos] = make_int2(src[e], __float_as_int(eattr[e]));
    }
}

// ---------------- per-layer node projection: xh = feat @ W (packed bf16), al_s/al_d dots ----------------
// xhb[n][w] (w=0..63) holds channels {2w, 2w+1} as 2x bf16; chans 0-63 = head0, 64-127 = head1.

template<int FIN>
__global__ __launch_bounds__(128) void node_proj_kernel(
        const float* __restrict__ feat, const float* __restrict__ W,
        const float* __restrict__ as_, const float* __restrict__ ad_,
        u32* __restrict__ xhb, float* __restrict__ al_s, float* __restrict__ al_d, int N) {
    __shared__ float sf[FIN];
    int n = blockIdx.x;
    if (n >= N) return;
    int j = threadIdx.x;  // 0..127  (h = j>>6, c = j&63)
    if (j < FIN) sf[j] = feat[(size_t)n * FIN + j];
    __syncthreads();
    float acc = 0.f;
#pragma unroll
    for (int k = 0; k < FIN; k++) acc += sf[k] * W[k * 128 + j];
    float hi = __shfl_down(acc, 1);
    if ((j & 1) == 0)
        xhb[(size_t)n * 64 + (j >> 1)] = (f2bf(hi) << 16) | f2bf(acc);
    float vs = acc * as_[j];
    float vd = acc * ad_[j];
#pragma unroll
    for (int m = 32; m >= 1; m >>= 1) {
        vs += __shfl_xor(vs, m);
        vd += __shfl_xor(vd, m);
    }
    if ((j & 63) == 0) {
        int h = j >> 6;
        al_s[n * 2 + h] = vs;
        al_d[n * 2 + h] = vd;
    }
}

// al_e[e,h] = eattr[e] * dot(We[h,:], ae[h,:])  -> precompute the 4 scalars (2 layers x 2 heads)
__global__ __launch_bounds__(256) void wedot_kernel(const float* __restrict__ We1, const float* __restrict__ ae1,
                                                    const float* __restrict__ We2, const float* __restrict__ ae2,
                                                    float* __restrict__ we_dot) {
    int t = threadIdx.x;
    int g = t >> 6, lane = t & 63;          // g = layer*2 + h
    const float* We = (g & 2) ? We2 : We1;
    const float* ae = (g & 2) ? ae2 : ae1;
    int h = g & 1;
    float v = We[h * 64 + lane] * ae[h * 64 + lane];
#pragma unroll
    for (int m = 32; m >= 1; m >>= 1) v += __shfl_xor(v, m);
    if (lane == 0) we_dot[g] = v;
}

// ---------------- edge aggregation: segment softmax + weighted sum, one wave per dst ----------------
// lane owns packed word `lane` = channels {2*lane, 2*lane+1}; lanes<32 head0, lanes>=32 head1.

__global__ __launch_bounds__(64) void edge_aggr_kernel(
        const int* __restrict__ row_ptr, const int2* __restrict__ col,
        const float2* __restrict__ al_s, const float2* __restrict__ al_d,
        const u32* __restrict__ xhb,
        const float* __restrict__ bias, const float* __restrict__ we_dot, int layer,
        float* __restrict__ out, int N) {
    __shared__ float s_ex0[64], s_ex1[64];
    __shared__ int s_src[64];
    int n = blockIdx.x;
    if (n >= N) return;
    int lane = threadIdx.x;
    int start = row_ptr[n], end = row_ptr[n + 1];
    int cnt = end - start;
    float we0 = we_dot[layer * 2], we1 = we_dot[layer * 2 + 1];
    float2 ald = al_d[n];

    float accx = 0.f, accy = 0.f, den0 = 0.f, den1 = 0.f;

    if (cnt <= 64) {
        // ---- fast path: single chunk, alpha computed once ----
        float a0 = -INFINITY, a1 = -INFINITY;
        int sc = 0;
        if (lane < cnt) {
            int2 ce = col[start + lane];
            sc = ce.x;
            float at = __int_as_float(ce.y);
            float2 als = al_s[sc];
            a0 = als.x + ald.x + we0 * at;
            a1 = als.y + ald.y + we1 * at;
            a0 = LRELU(a0); a1 = LRELU(a1);
        }
        float m0 = a0, m1 = a1;
#pragma unroll
        for (int m = 32; m >= 1; m >>= 1) {
            m0 = fmaxf(m0, __shfl_xor(m0, m));
            m1 = fmaxf(m1, __shfl_xor(m1, m));
        }
        float e0 = 0.f, e1 = 0.f;
        if (lane < cnt) {
            e0 = __expf(a0 - m0);
            e1 = __expf(a1 - m1);
        }
        den0 = e0; den1 = e1;
        s_ex0[lane] = e0; s_ex1[lane] = e1; s_src[lane] = sc;
        __syncthreads();

        const float* s_w = (lane < 32) ? s_ex0 : s_ex1;
#pragma unroll 4
        for (int j = 0; j < cnt; j++) {
            float w = s_w[j];
            u32 v = xhb[(size_t)s_src[j] * 64 + lane];
            accx += w * __uint_as_float(v << 16);
            accy += w * __uint_as_float(v & 0xffff0000u);
        }
    } else {
        // ---- general path (cnt > 64): chunked, same gather layout ----
        float m0 = -INFINITY, m1 = -INFINITY;
        for (int i = start + lane; i < end; i += 64) {
            int2 ce = col[i];
            float at = __int_as_float(ce.y);
            float2 als = al_s[ce.x];
            float a0 = als.x + ald.x + we0 * at;
            float a1 = als.y + ald.y + we1 * at;
            a0 = LRELU(a0); a1 = LRELU(a1);
            m0 = fmaxf(m0, a0); m1 = fmaxf(m1, a1);
        }
#pragma unroll
        for (int m = 32; m >= 1; m >>= 1) {
            m0 = fmaxf(m0, __shfl_xor(m0, m));
            m1 = fmaxf(m1, __shfl_xor(m1, m));
        }
        const float* s_w = (lane < 32) ? s_ex0 : s_ex1;
        for (int cs = start; cs < end; cs += 64) {
            int i = cs + lane;
            float e0 = 0.f, e1 = 0.f;
            int sc = 0;
            if (i < end) {
                int2 ce = col[i];
                sc = ce.x;
                float at = __int_as_float(ce.y);
                float2 als = al_s[sc];
                float a0 = als.x + ald.x + we0 * at;
                float a1 = als.y + ald.y + we1 * at;
                a0 = LRELU(a0); a1 = LRELU(a1);
                e0 = __expf(a0 - m0);
                e1 = __expf(a1 - m1);
            }
            den0 += e0; den1 += e1;
            s_ex0[lane] = e0; s_ex1[lane] = e1; s_src[lane] = sc;
            __syncthreads();
            int c2 = min(64, end - cs);
#pragma unroll 4
            for (int j = 0; j < c2; j++) {
                float w = s_w[j];
                u32 v = xhb[(size_t)s_src[j] * 64 + lane];
                accx += w * __uint_as_float(v << 16);
                accy += w * __uint_as_float(v & 0xffff0000u);
            }
            __syncthreads();
        }
    }

#pragma unroll
    for (int m = 32; m >= 1; m >>= 1) {
        den0 += __shfl_xor(den0, m);
        den1 += __shfl_xor(den1, m);
    }
    float inv0 = 1.f / (den0 + 1e-16f), inv1 = 1.f / (den1 + 1e-16f);
    float px = __shfl_xor(accx, 32);   // partner head's partials, same channels
    float py = __shfl_xor(accy, 32);
    if (lane < 32) {
        float2 bv = ((const float2*)bias)[lane];
        float ox = 0.5f * (accx * inv0 + px * inv1) + bv.x;
        float oy = 0.5f * (accy * inv0 + py * inv1) + bv.y;
        ((float2*)out)[(size_t)n * 32 + lane] = make_float2(fmaxf(ox, 0.f), fmaxf(oy, 0.f));
    }
}

// ---------------- pooling: hierarchical (LDS bins -> few global atomics) ----------------

__global__ __launch_bounds__(256) void pool_kernel(const float* __restrict__ feat,
                                                   const float* __restrict__ Wlin, const int* __restrict__ batch,
                                                   float* __restrict__ pool_sum, int* __restrict__ pool_cnt, int N) {
    __shared__ float s_sum[64];
    __shared__ int s_cnt[64];
    int t = threadIdx.x;
    if (t < 64) { s_sum[t] = 0.f; s_cnt[t] = 0; }
    __syncthreads();

    int nblk = gridDim.x;
    int chunk = (N + nblk - 1) / nblk;
    int lo = blockIdx.x * chunk;
    int hi = min(lo + chunk, N);
    int lane = t & 63;
    float wl = Wlin[lane];

    for (int node = lo + (t >> 6); node < hi; node += 4) {
        float v = feat[(size_t)node * 64 + lane] * wl;
#pragma unroll
        for (int m = 32; m >= 1; m >>= 1) v += __shfl_xor(v, m);
        if (lane == 0) {
            int g = batch[node];
            atomicAdd(&s_sum[g], v);
            atomicAdd(&s_cnt[g], 1);
        }
    }
    __syncthreads();
    if (t < 64 && s_cnt[t] > 0) {
        atomicAdd(&pool_sum[t], s_sum[t]);
        atomicAdd(&pool_cnt[t], s_cnt[t]);
    }
}

__global__ void final_kernel(const float* __restrict__ pool_sum, const int* __restrict__ pool_cnt,
                             const float* __restrict__ blin, float* __restrict__ out) {
    int g = threadIdx.x;
    if (g < 64) out[g] = pool_sum[g] / fmaxf((float)pool_cnt[g], 1.f) + blin[0];
}

// ---------------- launch ----------------

extern "C" void kernel_launch(void* const* d_in, const int* in_sizes, int n_in,
                              void* d_out, int out_size, void* d_ws, size_t ws_size,
                              hipStream_t stream) {
    const float* x     = (const float*)d_in[0];
    const int*   ei    = (const int*)d_in[1];
    const float* eattr = (const float*)d_in[2];
    const int*   batch = (const int*)d_in[3];
    const float* W1  = (const float*)d_in[4];
    const float* as1 = (const float*)d_in[5];
    const float* ad1 = (const float*)d_in[6];
    const float* We1 = (const float*)d_in[7];
    const float* ae1 = (const float*)d_in[8];
    const float* b1  = (const float*)d_in[9];
    const float* W2  = (const float*)d_in[10];
    const float* as2 = (const float*)d_in[11];
    const float* ad2 = (const float*)d_in[12];
    const float* We2 = (const float*)d_in[13];
    const float* ae2 = (const float*)d_in[14];
    const float* b2  = (const float*)d_in[15];
    const float* Wlin = (const float*)d_in[16];
    const float* blin = (const float*)d_in[17];
    float* out = (float*)d_out;

    int N = in_sizes[0] / 5;
    int E = in_sizes[1] / 2;
    size_t EP = (size_t)E + N;
    const int* src0 = ei;
    const int* dst0 = ei + E;
    int B = (N + 255) / 256;   // blocks for node-chunked scan (must be <= 1024)

    char* ws = (char*)d_ws;
    size_t off = 0;
    auto alloc = [&](size_t bytes) {
        void* p = ws + off;
        off = (off + bytes + 255) & ~(size_t)255;
        return p;
    };
    unsigned long long* hist = (unsigned long long*)alloc((size_t)N * 8);
    int*   row_ptr  = (int*)  alloc((size_t)(N + 1) * 4);
    int*   cursor   = (int*)  alloc((size_t)N * 4);
    int2*  col      = (int2*) alloc(EP * 8);
    int*   block_sum= (int*)  alloc((size_t)1024 * 4);
    int*   block_off= (int*)  alloc((size_t)1024 * 4);
    float* al_s     = (float*)alloc((size_t)N * 2 * 4);
    float* al_d     = (float*)alloc((size_t)N * 2 * 4);
    u32*   xhb      = (u32*)  alloc((size_t)N * 64 * 4);   // packed bf16x2
    float* feat1    = (float*)alloc((size_t)N * 64 * 4);
    float* feat2    = (float*)alloc((size_t)N * 64 * 4);
    float* we_dot   = (float*)alloc(4 * 4);
    float* pool_sum = (float*)alloc(64 * 4);
    int*   pool_cnt = (int*)  alloc(64 * 4);

    hipMemsetAsync(hist, 0, (size_t)N * 8, stream);
    hipMemsetAsync(block_sum, 0, (size_t)1024 * 4, stream);
    hipMemsetAsync(pool_sum, 0, 64 * 4, stream);
    hipMemsetAsync(pool_cnt, 0, 64 * 4, stream);

    hist_kernel<<<(E + 255) / 256, 256, 0, stream>>>(dst0, eattr, hist, E);
    scan_phase1<<<B, 256, 0, stream>>>(hist, block_sum, N);
    scan_phase2<<<1, 1024, 0, stream>>>(block_sum, block_off, row_ptr, B, N);
    scan_phase3<<<B, 256, 0, stream>>>(hist, block_off, row_ptr, cursor, col, N);
    scatter_kernel<<<(E + 255) / 256, 256, 0, stream>>>(src0, dst0, eattr, cursor, col, E);
    wedot_kernel<<<1, 256, 0, stream>>>(We1, ae1, We2, ae2, we_dot);

    // layer 1
    node_proj_kernel<5><<<N, 128, 0, stream>>>(x, W1, as1, ad1, xhb, al_s, al_d, N);
    edge_aggr_kernel<<<N, 64, 0, stream>>>(row_ptr, col, (const float2*)al_s, (const float2*)al_d,
                                           xhb, b1, we_dot, 0, feat1, N);
    // layer 2
    node_proj_kernel<64><<<N, 128, 0, stream>>>(feat1, W2, as2, ad2, xhb, al_s, al_d, N);
    edge_aggr_kernel<<<N, 64, 0, stream>>>(row_ptr, col, (const float2*)al_s, (const float2*)al_d,
                                           xhb, b2, we_dot, 1, feat2, N);
    // pool + linear (hierarchical: LDS bins then ~2 global atomics per block)
    pool_kernel<<<512, 256, 0, stream>>>(feat2, Wlin, batch, pool_sum, pool_cnt, N);
    final_kernel<<<1, 64, 0, stream>>>(pool_sum, pool_cnt, blin, out);
}